// Round 6
// baseline (101.077 us; speedup 1.0000x reference)
//
#include <hip/hip_runtime.h>

using bf16x8 = __attribute__((ext_vector_type(8))) short;
using f32x4  = __attribute__((ext_vector_type(4))) float;

#define ND      2048
#define NOUT    192
#define TSEQ    4096
#define NCH     32            // 2048 / 64
#define ZP      204           // zbuf row stride (floats, bank-staggered)

#define OFF_PRE  4194304      // K*B*T*16
#define OFF_POST 5242880      // + K*B*T*4

__device__ __forceinline__ float sigmoidf_(float v) {
    return 1.0f / (1.0f + __expf(-v));
}
__device__ __forceinline__ unsigned f2bf(float f) {   // RNE float->bf16 bits
    unsigned u = __float_as_uint(f);
    u += 0x7fffu + ((u >> 16) & 1u);
    return u >> 16;
}
// robust to active_idx arriving as int32 or int64 (low-word read)
__device__ __forceinline__ int get_expert(const int* __restrict__ act, int k) {
    const bool odd_zero = (act[1] == 0) & (act[3] == 0) & (act[5] == 0) & (act[7] == 0);
    const bool even_any = (act[0] | act[2] | act[4] | act[6]) != 0;
    const bool is64 = odd_zero & even_any;
    return is64 ? act[2 * k] : act[k];
}

// -------- pass 1: Wb[o][d] = bf16( phi[e_k, j, d] * norm_w[e_k, d] ) --------
__global__ __launch_bounds__(256) void prep_w_kernel(
    const float* __restrict__ norm_w,
    const float* __restrict__ p_pre,
    const float* __restrict__ p_post,
    const float* __restrict__ p_res,
    const int* __restrict__ act,
    short* __restrict__ Wb)
{
    const int o = blockIdx.x;           // 0..191
    const int k = o / 24, j = o % 24;
    const int e = get_expert(act, k);
    const float* src;
    if (j < 4)      src = p_pre  + ((size_t)e * 4  + j)       * ND;
    else if (j < 8) src = p_post + ((size_t)e * 4  + (j - 4)) * ND;
    else            src = p_res  + ((size_t)e * 16 + (j - 8)) * ND;
    const float* nw = norm_w + (size_t)e * ND;
    short* dst = Wb + (size_t)o * ND;
    for (int d = threadIdx.x * 4; d < ND; d += 1024) {
        float4 a = *(const float4*)(src + d);
        float4 b = *(const float4*)(nw + d);
        uint2 w;
        w.x = f2bf(a.x * b.x) | (f2bf(a.y * b.y) << 16);
        w.y = f2bf(a.z * b.z) | (f2bf(a.w * b.w) << 16);
        *(uint2*)(dst + d) = w;
    }
}

// -------- pass 2: fused rms + MFMA GEMM + sigmoid/sinkhorn epilogue --------
// 512 blocks x 256 threads (4 waves). Block tile: 64 rows x 192 cols, KC=64.
// LDS 16B units, XOR-swizzled (conflict-free writes AND reads). ALL LDS
// accesses typed bf16x8 (uint4-write/bf16x8-read TBAA broke R2/R3).
// Register prefetch distance 2 (named A/B buffer sets, static indexing).
__global__ __launch_bounds__(256) void mhc_mfma_kernel(
    const float* __restrict__ xin,      // (B, 4, T, 512) fp32
    const short* __restrict__ Wb,       // (192, 2048) bf16 bits
    const int* __restrict__ act,
    const float* __restrict__ b_pre, const float* __restrict__ b_post,
    const float* __restrict__ b_res,
    const float* __restrict__ a_pre, const float* __restrict__ a_post,
    const float* __restrict__ a_res,
    float* __restrict__ out)
{
    __shared__ union SU {
        struct {
            alignas(16) short Xs[8 * 64 * 8];    // [g][m^g][8]
            alignas(16) short Ws[8 * 192 * 8];   // [g][n^g][8]
        } s;
        float zbuf[64][ZP];
    } u;
    __shared__ float sqpart[64][8];
    __shared__ float inv_rms[64];

    const int tid  = threadIdx.x;
    const int lane = tid & 63;
    const int wid  = tid >> 6;
    const int wr = wid >> 1, wc = wid & 1;      // wave -> (rowgrp, colgrp)
    const int m0 = blockIdx.x << 6;
    const int bb = m0 >> 12, t0 = m0 & (TSEQ - 1);
    const int gx  = tid & 7;                    // staging k-octet
    const int xmr = tid >> 3;                   // staging row (and +32)
    const int lrow = lane & 15, lhi = lane >> 4;

    f32x4 acc[2][6];
#pragma unroll
    for (int a_ = 0; a_ < 2; ++a_)
#pragma unroll
        for (int b_ = 0; b_ < 6; ++b_) {
            f32x4 z; z[0] = 0.f; z[1] = 0.f; z[2] = 0.f; z[3] = 0.f;
            acc[a_][b_] = z;
        }

    float ssq0 = 0.f, ssq1 = 0.f;
    float4 a0A, a1A, c0A, c1A;  bf16x8 wvA[6];
    float4 a0B, a1B, c0B, c1B;  bf16x8 wvB[6];

#define ISSUE_LOADS(ch_, A0, A1, C0, C1, WV) do {                             \
    const int ch__ = (ch_);                                                   \
    const float* xb = xin                                                     \
        + ((size_t)(bb * 4 + (ch__ >> 3)) * TSEQ + t0) * 512 + ((ch__ & 7) << 6); \
    A0 = *(const float4*)(xb + xmr * 512 + gx * 8);                           \
    A1 = *(const float4*)(xb + xmr * 512 + gx * 8 + 4);                       \
    C0 = *(const float4*)(xb + (xmr + 32) * 512 + gx * 8);                    \
    C1 = *(const float4*)(xb + (xmr + 32) * 512 + gx * 8 + 4);                \
    const short* wch = Wb + ch__ * 64;                                        \
    _Pragma("unroll")                                                         \
    for (int j_ = 0; j_ < 6; ++j_) {                                          \
        const int uidx = tid + 256 * j_;                                      \
        const int n_ = uidx >> 3, g_ = uidx & 7;                              \
        WV[j_] = *(const bf16x8*)(wch + n_ * 2048 + g_ * 8);                  \
    }                                                                         \
} while (0)

#define STAGE(A0, A1, C0, C1, WV) do {                                        \
    ssq0 += A0.x*A0.x + A0.y*A0.y + A0.z*A0.z + A0.w*A0.w                     \
          + A1.x*A1.x + A1.y*A1.y + A1.z*A1.z + A1.w*A1.w;                    \
    bf16x8 pk;                                                                \
    pk[0] = (short)f2bf(A0.x); pk[1] = (short)f2bf(A0.y);                     \
    pk[2] = (short)f2bf(A0.z); pk[3] = (short)f2bf(A0.w);                     \
    pk[4] = (short)f2bf(A1.x); pk[5] = (short)f2bf(A1.y);                     \
    pk[6] = (short)f2bf(A1.z); pk[7] = (short)f2bf(A1.w);                     \
    *(bf16x8*)&u.s.Xs[(gx * 64 + (xmr ^ gx)) * 8] = pk;                       \
    ssq1 += C0.x*C0.x + C0.y*C0.y + C0.z*C0.z + C0.w*C0.w                     \
          + C1.x*C1.x + C1.y*C1.y + C1.z*C1.z + C1.w*C1.w;                    \
    bf16x8 pk2;                                                               \
    pk2[0] = (short)f2bf(C0.x); pk2[1] = (short)f2bf(C0.y);                   \
    pk2[2] = (short)f2bf(C0.z); pk2[3] = (short)f2bf(C0.w);                   \
    pk2[4] = (short)f2bf(C1.x); pk2[5] = (short)f2bf(C1.y);                   \
    pk2[6] = (short)f2bf(C1.z); pk2[7] = (short)f2bf(C1.w);                   \
    *(bf16x8*)&u.s.Xs[(gx * 64 + ((xmr + 32) ^ gx)) * 8] = pk2;               \
    _Pragma("unroll")                                                         \
    for (int j_ = 0; j_ < 6; ++j_) {                                          \
        const int uidx = tid + 256 * j_;                                      \
        const int n_ = uidx >> 3, g_ = uidx & 7;                              \
        *(bf16x8*)&u.s.Ws[(g_ * 192 + (n_ ^ g_)) * 8] = WV[j_];               \
    }                                                                         \
} while (0)

#define MFMA_PHASE() do {                                                     \
    _Pragma("unroll")                                                         \
    for (int ks = 0; ks < 2; ++ks) {                                          \
        const int g_ = ks * 4 + lhi;                                          \
        bf16x8 af[2], bfv[6];                                                 \
        _Pragma("unroll")                                                     \
        for (int mt = 0; mt < 2; ++mt)                                        \
            af[mt] = *(const bf16x8*)                                         \
                &u.s.Xs[(g_ * 64 + ((wr * 32 + mt * 16 + lrow) ^ g_)) * 8];   \
        _Pragma("unroll")                                                     \
        for (int nt = 0; nt < 6; ++nt)                                        \
            bfv[nt] = *(const bf16x8*)                                        \
                &u.s.Ws[(g_ * 192 + ((wc * 96 + nt * 16 + lrow) ^ g_)) * 8];  \
        _Pragma("unroll")                                                     \
        for (int mt = 0; mt < 2; ++mt)                                        \
            _Pragma("unroll")                                                 \
            for (int nt = 0; nt < 6; ++nt)                                    \
                acc[mt][nt] = __builtin_amdgcn_mfma_f32_16x16x32_bf16(        \
                    af[mt], bfv[nt], acc[mt][nt], 0, 0, 0);                   \
    }                                                                         \
} while (0)

    ISSUE_LOADS(0, a0A, a1A, c0A, c1A, wvA);    // prologue: chunks 0 and 1
    ISSUE_LOADS(1, a0B, a1B, c0B, c1B, wvB);

    for (int ch = 0; ch < NCH; ch += 2) {
        __syncthreads();                        // prev readers done
        STAGE(a0A, a1A, c0A, c1A, wvA);
        __syncthreads();                        // staged visible
        if (ch + 2 < NCH) ISSUE_LOADS(ch + 2, a0A, a1A, c0A, c1A, wvA);
        MFMA_PHASE();

        __syncthreads();
        STAGE(a0B, a1B, c0B, c1B, wvB);
        __syncthreads();
        if (ch + 3 < NCH) ISSUE_LOADS(ch + 3, a0B, a1B, c0B, c1B, wvB);
        MFMA_PHASE();
    }

    // ---- rms ----
    sqpart[xmr][gx]      = ssq0;
    sqpart[xmr + 32][gx] = ssq1;
    __syncthreads();
    if (tid < 64) {
        const float* sp = sqpart[tid];
        const float s_ = sp[0] + sp[1] + sp[2] + sp[3] + sp[4] + sp[5] + sp[6] + sp[7];
        inv_rms[tid] = 1.0f / sqrtf(s_ * (1.0f / ND) + 1e-8f);
    }
    __syncthreads();

    // ---- z scatter (C/D: col=lane&15, row=(lane>>4)*4+reg; R4 HW-probed) ----
#pragma unroll
    for (int mt = 0; mt < 2; ++mt) {
#pragma unroll
        for (int r = 0; r < 4; ++r) {
            const int row = wr * 32 + mt * 16 + lhi * 4 + r;
            const float ir = inv_rms[row];
#pragma unroll
            for (int nt = 0; nt < 6; ++nt) {
                const int n = wc * 96 + nt * 16 + lrow;
                u.zbuf[row][n] = acc[mt][nt][r] * ir;
            }
        }
    }
    __syncthreads();

    // ---- epilogue: 512 (row, k) problems, 2 per thread ----
#pragma unroll
    for (int pi = 0; pi < 2; ++pi) {
        const int p   = tid + pi * 256;
        const int row = p >> 3;
        const int k   = p & 7;
        const int e   = get_expert(act, k);

        float z[24];
#pragma unroll
        for (int j6 = 0; j6 < 6; ++j6) {
            float4 v = *(const float4*)&u.zbuf[row][k * 24 + j6 * 4];
            z[j6 * 4 + 0] = v.x; z[j6 * 4 + 1] = v.y;
            z[j6 * 4 + 2] = v.z; z[j6 * 4 + 3] = v.w;
        }

        const int m = m0 + row;
        const int b = m >> 12;
        const int t = m & (TSEQ - 1);
        const size_t kbt = (size_t)(k * 8 + b) * TSEQ + t;

        {   // H_pre
            const float al = a_pre[e];
            float4 o4;
            o4.x = sigmoidf_(al * z[0] + b_pre[e * 4 + 0]);
            o4.y = sigmoidf_(al * z[1] + b_pre[e * 4 + 1]);
            o4.z = sigmoidf_(al * z[2] + b_pre[e * 4 + 2]);
            o4.w = sigmoidf_(al * z[3] + b_pre[e * 4 + 3]);
            *(float4*)(out + OFF_PRE + kbt * 4) = o4;
        }
        {   // H_post
            const float al = a_post[e];
            float4 o4;
            o4.x = 2.f * sigmoidf_(al * z[4] + b_post[e * 4 + 0]);
            o4.y = 2.f * sigmoidf_(al * z[5] + b_post[e * 4 + 1]);
            o4.z = 2.f * sigmoidf_(al * z[6] + b_post[e * 4 + 2]);
            o4.w = 2.f * sigmoidf_(al * z[7] + b_post[e * 4 + 3]);
            *(float4*)(out + OFF_POST + kbt * 4) = o4;
        }
        {   // H_res: exp + 6x sinkhorn (row-normalize then col-normalize)
            const float al = a_res[e];
            float P[16];
#pragma unroll
            for (int mm = 0; mm < 16; ++mm)
                P[mm] = __expf(al * z[8 + mm] + b_res[e * 16 + mm]);
#pragma unroll
            for (int it = 0; it < 6; ++it) {
#pragma unroll
                for (int i = 0; i < 4; ++i) {
                    const float s = P[i*4] + P[i*4+1] + P[i*4+2] + P[i*4+3];
                    const float rs = 1.0f / s;
                    P[i*4] *= rs; P[i*4+1] *= rs; P[i*4+2] *= rs; P[i*4+3] *= rs;
                }
#pragma unroll
                for (int jj = 0; jj < 4; ++jj) {
                    const float s = P[jj] + P[4+jj] + P[8+jj] + P[12+jj];
                    const float rs = 1.0f / s;
                    P[jj] *= rs; P[4+jj] *= rs; P[8+jj] *= rs; P[12+jj] *= rs;
                }
            }
#pragma unroll
            for (int i = 0; i < 4; ++i) {
                float4 o4;
                o4.x = P[i*4]; o4.y = P[i*4+1]; o4.z = P[i*4+2]; o4.w = P[i*4+3];
                *(float4*)(out + kbt * 16 + i * 4) = o4;
            }
        }
    }
#undef ISSUE_LOADS
#undef STAGE
#undef MFMA_PHASE
}

extern "C" void kernel_launch(void* const* d_in, const int* in_sizes, int n_in,
                              void* d_out, int out_size, void* d_ws, size_t ws_size,
                              hipStream_t stream) {
    const float* x      = (const float*)d_in[0];
    const int*   act    = (const int*)d_in[1];
    const float* norm_w = (const float*)d_in[2];
    const float* p_pre  = (const float*)d_in[3];
    const float* p_post = (const float*)d_in[4];
    const float* p_res  = (const float*)d_in[5];
    const float* b_pre  = (const float*)d_in[6];
    const float* b_post = (const float*)d_in[7];
    const float* b_res  = (const float*)d_in[8];
    const float* a_pre  = (const float*)d_in[9];
    const float* a_post = (const float*)d_in[10];
    const float* a_res  = (const float*)d_in[11];
    short* Wb  = (short*)d_ws;              // 192*2048 bf16 = 786 KB
    float* out = (float*)d_out;

    prep_w_kernel<<<dim3(NOUT), dim3(256), 0, stream>>>(
        norm_w, p_pre, p_post, p_res, act, Wb);
    mhc_mfma_kernel<<<dim3(512), dim3(256), 0, stream>>>(
        x, Wb, act, b_pre, b_post, b_res, a_pre, a_post, a_res, out);
}

// Round 9
// 76.021 us; speedup vs baseline: 1.3296x; 1.3296x over previous
//
#include <hip/hip_runtime.h>

using bf16x8 = __attribute__((ext_vector_type(8))) short;
using f32x4  = __attribute__((ext_vector_type(4))) float;

#define ND      2048
#define NOUT    192
#define TSEQ    4096
#define NCH     32            // 2048 / 64
#define ZP      196           // zbuf row stride (floats; 192 used, 16B-aligned)

#define OFF_PRE  4194304      // K*B*T*16
#define OFF_POST 5242880      // + K*B*T*4

__device__ __forceinline__ float sigmoidf_(float v) {
    return 1.0f / (1.0f + __expf(-v));
}
__device__ __forceinline__ unsigned f2bf(float f) {   // RNE float->bf16 bits
    unsigned u = __float_as_uint(f);
    u += 0x7fffu + ((u >> 16) & 1u);
    return u >> 16;
}
// robust to active_idx arriving as int32 or int64 (low-word read)
__device__ __forceinline__ int get_expert(const int* __restrict__ act, int k) {
    const bool odd_zero = (act[1] == 0) & (act[3] == 0) & (act[5] == 0) & (act[7] == 0);
    const bool even_any = (act[0] | act[2] | act[4] | act[6]) != 0;
    const bool is64 = odd_zero & even_any;
    return is64 ? act[2 * k] : act[k];
}

// -------- pass 1: Wb[o][d] = bf16( phi[e_k, j, d] * norm_w[e_k, d] ) --------
__global__ __launch_bounds__(256) void prep_w_kernel(
    const float* __restrict__ norm_w,
    const float* __restrict__ p_pre,
    const float* __restrict__ p_post,
    const float* __restrict__ p_res,
    const int* __restrict__ act,
    short* __restrict__ Wb)
{
    const int o = blockIdx.x;           // 0..191
    const int k = o / 24, j = o % 24;
    const int e = get_expert(act, k);
    const float* src;
    if (j < 4)      src = p_pre  + ((size_t)e * 4  + j)       * ND;
    else if (j < 8) src = p_post + ((size_t)e * 4  + (j - 4)) * ND;
    else            src = p_res  + ((size_t)e * 16 + (j - 8)) * ND;
    const float* nw = norm_w + (size_t)e * ND;
    short* dst = Wb + (size_t)o * ND;
    for (int d = threadIdx.x * 4; d < ND; d += 1024) {
        float4 a = *(const float4*)(src + d);
        float4 b = *(const float4*)(nw + d);
        uint2 w;
        w.x = f2bf(a.x * b.x) | (f2bf(a.y * b.y) << 16);
        w.y = f2bf(a.z * b.z) | (f2bf(a.w * b.w) << 16);
        *(uint2*)(dst + d) = w;
    }
}

// -------- pass 2: fused rms + MFMA GEMM + sigmoid/sinkhorn epilogue --------
// 512 blocks x 256 threads (4 waves). Block tile: 64 rows x 192 cols, KC=64.
// R5-proven K-loop + single-pass epilogue VERBATIM. LDS diet only:
//   zbuf [64][196] (was 204) and shfl-based rms (sqpart LDS removed)
// -> ~50.4 KB -> 3 blocks/CU (was 2): occupancy-driven latency hiding.
// ALL LDS staging accesses typed bf16x8 (uint4/bf16x8 mix broke R2/R3).
__global__ __launch_bounds__(256) void mhc_mfma_kernel(
    const float* __restrict__ xin,      // (B, 4, T, 512) fp32
    const short* __restrict__ Wb,       // (192, 2048) bf16 bits
    const int* __restrict__ act,
    const float* __restrict__ b_pre, const float* __restrict__ b_post,
    const float* __restrict__ b_res,
    const float* __restrict__ a_pre, const float* __restrict__ a_post,
    const float* __restrict__ a_res,
    float* __restrict__ out)
{
    __shared__ union SU {
        struct {
            alignas(16) short Xs[8 * 64 * 8];    // [g][m^g][8]  (8 KB)
            alignas(16) short Ws[8 * 192 * 8];   // [g][n^g][8]  (24 KB)
        } s;
        float zbuf[64][ZP];                      // 50.2 KB
    } u;
    __shared__ float inv_rms[64];

    const int tid  = threadIdx.x;
    const int lane = tid & 63;
    const int wid  = tid >> 6;
    const int wr = wid >> 1, wc = wid & 1;      // wave -> (rowgrp, colgrp)
    const int m0 = blockIdx.x << 6;
    const int bb = m0 >> 12, t0 = m0 & (TSEQ - 1);
    const int gx  = tid & 7;                    // staging k-octet
    const int xmr = tid >> 3;                   // staging row (and +32)
    const int lrow = lane & 15, lhi = lane >> 4;

    f32x4 acc[2][6];
#pragma unroll
    for (int a_ = 0; a_ < 2; ++a_)
#pragma unroll
        for (int b_ = 0; b_ < 6; ++b_) {
            f32x4 z; z[0] = 0.f; z[1] = 0.f; z[2] = 0.f; z[3] = 0.f;
            acc[a_][b_] = z;
        }

    float ssq0 = 0.f, ssq1 = 0.f;
    float4 a0, a1, c0, c1;
    bf16x8 wv[6];

    auto issue_loads = [&](int ch) {
        const float* xb = xin
            + ((size_t)(bb * 4 + (ch >> 3)) * TSEQ + t0) * 512 + ((ch & 7) << 6);
        a0 = *(const float4*)(xb + xmr * 512 + gx * 8);
        a1 = *(const float4*)(xb + xmr * 512 + gx * 8 + 4);
        c0 = *(const float4*)(xb + (xmr + 32) * 512 + gx * 8);
        c1 = *(const float4*)(xb + (xmr + 32) * 512 + gx * 8 + 4);
        const short* wch = Wb + ch * 64;
#pragma unroll
        for (int j = 0; j < 6; ++j) {
            const int uidx = tid + 256 * j;     // 0..1535
            const int n = uidx >> 3, g = uidx & 7;
            wv[j] = *(const bf16x8*)(wch + n * 2048 + g * 8);
        }
    };

    issue_loads(0);                             // prologue

    for (int ch = 0; ch < NCH; ++ch) {
        __syncthreads();                        // (A) prev-chunk readers done

        // ---- convert + stage X (swizzled), accumulate ssq ----
        {
            ssq0 += a0.x*a0.x + a0.y*a0.y + a0.z*a0.z + a0.w*a0.w
                  + a1.x*a1.x + a1.y*a1.y + a1.z*a1.z + a1.w*a1.w;
            bf16x8 pk;
            pk[0] = (short)f2bf(a0.x); pk[1] = (short)f2bf(a0.y);
            pk[2] = (short)f2bf(a0.z); pk[3] = (short)f2bf(a0.w);
            pk[4] = (short)f2bf(a1.x); pk[5] = (short)f2bf(a1.y);
            pk[6] = (short)f2bf(a1.z); pk[7] = (short)f2bf(a1.w);
            *(bf16x8*)&u.s.Xs[(gx * 64 + (xmr ^ gx)) * 8] = pk;
        }
        {
            ssq1 += c0.x*c0.x + c0.y*c0.y + c0.z*c0.z + c0.w*c0.w
                  + c1.x*c1.x + c1.y*c1.y + c1.z*c1.z + c1.w*c1.w;
            bf16x8 pk;
            pk[0] = (short)f2bf(c0.x); pk[1] = (short)f2bf(c0.y);
            pk[2] = (short)f2bf(c0.z); pk[3] = (short)f2bf(c0.w);
            pk[4] = (short)f2bf(c1.x); pk[5] = (short)f2bf(c1.y);
            pk[6] = (short)f2bf(c1.z); pk[7] = (short)f2bf(c1.w);
            *(bf16x8*)&u.s.Xs[(gx * 64 + ((xmr + 32) ^ gx)) * 8] = pk;
        }
#pragma unroll
        for (int j = 0; j < 6; ++j) {
            const int uidx = tid + 256 * j;
            const int n = uidx >> 3, g = uidx & 7;
            *(bf16x8*)&u.s.Ws[(g * 192 + (n ^ g)) * 8] = wv[j];
        }
        __syncthreads();                        // (B) staged data visible

        // ---- prefetch next chunk: overlaps MFMA + next barrier wait ----
        if (ch + 1 < NCH) issue_loads(ch + 1);

        // ---- MFMA over chunk ----
#pragma unroll
        for (int ks = 0; ks < 2; ++ks) {
            const int g = ks * 4 + lhi;
            bf16x8 af[2], bfv[6];
#pragma unroll
            for (int mt = 0; mt < 2; ++mt)
                af[mt] = *(const bf16x8*)
                    &u.s.Xs[(g * 64 + ((wr * 32 + mt * 16 + lrow) ^ g)) * 8];
#pragma unroll
            for (int nt = 0; nt < 6; ++nt)
                bfv[nt] = *(const bf16x8*)
                    &u.s.Ws[(g * 192 + ((wc * 96 + nt * 16 + lrow) ^ g)) * 8];
#pragma unroll
            for (int mt = 0; mt < 2; ++mt)
#pragma unroll
                for (int nt = 0; nt < 6; ++nt)
                    acc[mt][nt] = __builtin_amdgcn_mfma_f32_16x16x32_bf16(
                        af[mt], bfv[nt], acc[mt][nt], 0, 0, 0);
        }
    }

    // ---- rms: 8-lane butterfly over gx (lanes xmr*8+gx are consecutive) ----
    ssq0 += __shfl_xor(ssq0, 1); ssq0 += __shfl_xor(ssq0, 2); ssq0 += __shfl_xor(ssq0, 4);
    ssq1 += __shfl_xor(ssq1, 1); ssq1 += __shfl_xor(ssq1, 2); ssq1 += __shfl_xor(ssq1, 4);
    if (gx == 0) {
        inv_rms[xmr]      = 1.0f / sqrtf(ssq0 * (1.0f / ND) + 1e-8f);
        inv_rms[xmr + 32] = 1.0f / sqrtf(ssq1 * (1.0f / ND) + 1e-8f);
    }
    __syncthreads();        // inv_rms visible; all MFMA LDS reads drained

    // ---- z scatter (C/D: col=lane&15, row=(lane>>4)*4+reg; R4 HW-probed) ----
#pragma unroll
    for (int mt = 0; mt < 2; ++mt) {
#pragma unroll
        for (int r = 0; r < 4; ++r) {
            const int row = wr * 32 + mt * 16 + lhi * 4 + r;
            const float ir = inv_rms[row];
#pragma unroll
            for (int nt = 0; nt < 6; ++nt) {
                const int n = wc * 96 + nt * 16 + lrow;
                u.zbuf[row][n] = acc[mt][nt][r] * ir;
            }
        }
    }
    __syncthreads();

    // ---- epilogue: 512 (row, k) problems, 2 per thread ----
#pragma unroll
    for (int pi = 0; pi < 2; ++pi) {
        const int p   = tid + pi * 256;
        const int row = p >> 3;
        const int k   = p & 7;
        const int e   = get_expert(act, k);

        float z[24];
#pragma unroll
        for (int j6 = 0; j6 < 6; ++j6) {
            float4 v = *(const float4*)&u.zbuf[row][k * 24 + j6 * 4];
            z[j6 * 4 + 0] = v.x; z[j6 * 4 + 1] = v.y;
            z[j6 * 4 + 2] = v.z; z[j6 * 4 + 3] = v.w;
        }

        const int m = m0 + row;
        const int b = m >> 12;
        const int t = m & (TSEQ - 1);
        const size_t kbt = (size_t)(k * 8 + b) * TSEQ + t;

        {   // H_pre
            const float al = a_pre[e];
            float4 o4;
            o4.x = sigmoidf_(al * z[0] + b_pre[e * 4 + 0]);
            o4.y = sigmoidf_(al * z[1] + b_pre[e * 4 + 1]);
            o4.z = sigmoidf_(al * z[2] + b_pre[e * 4 + 2]);
            o4.w = sigmoidf_(al * z[3] + b_pre[e * 4 + 3]);
            *(float4*)(out + OFF_PRE + kbt * 4) = o4;
        }
        {   // H_post
            const float al = a_post[e];
            float4 o4;
            o4.x = 2.f * sigmoidf_(al * z[4] + b_post[e * 4 + 0]);
            o4.y = 2.f * sigmoidf_(al * z[5] + b_post[e * 4 + 1]);
            o4.z = 2.f * sigmoidf_(al * z[6] + b_post[e * 4 + 2]);
            o4.w = 2.f * sigmoidf_(al * z[7] + b_post[e * 4 + 3]);
            *(float4*)(out + OFF_POST + kbt * 4) = o4;
        }
        {   // H_res: exp + 6x sinkhorn (row-normalize then col-normalize)
            const float al = a_res[e];
            float P[16];
#pragma unroll
            for (int mm = 0; mm < 16; ++mm)
                P[mm] = __expf(al * z[8 + mm] + b_res[e * 16 + mm]);
#pragma unroll
            for (int it = 0; it < 6; ++it) {
#pragma unroll
                for (int i = 0; i < 4; ++i) {
                    const float s = P[i*4] + P[i*4+1] + P[i*4+2] + P[i*4+3];
                    const float rs = 1.0f / s;
                    P[i*4] *= rs; P[i*4+1] *= rs; P[i*4+2] *= rs; P[i*4+3] *= rs;
                }
#pragma unroll
                for (int jj = 0; jj < 4; ++jj) {
                    const float s = P[jj] + P[4+jj] + P[8+jj] + P[12+jj];
                    const float rs = 1.0f / s;
                    P[jj] *= rs; P[4+jj] *= rs; P[8+jj] *= rs; P[12+jj] *= rs;
                }
            }
#pragma unroll
            for (int i = 0; i < 4; ++i) {
                float4 o4;
                o4.x = P[i*4]; o4.y = P[i*4+1]; o4.z = P[i*4+2]; o4.w = P[i*4+3];
                *(float4*)(out + kbt * 16 + i * 4) = o4;
            }
        }
    }
}

extern "C" void kernel_launch(void* const* d_in, const int* in_sizes, int n_in,
                              void* d_out, int out_size, void* d_ws, size_t ws_size,
                              hipStream_t stream) {
    const float* x      = (const float*)d_in[0];
    const int*   act    = (const int*)d_in[1];
    const float* norm_w = (const float*)d_in[2];
    const float* p_pre  = (const float*)d_in[3];
    const float* p_post = (const float*)d_in[4];
    const float* p_res  = (const float*)d_in[5];
    const float* b_pre  = (const float*)d_in[6];
    const float* b_post = (const float*)d_in[7];
    const float* b_res  = (const float*)d_in[8];
    const float* a_pre  = (const float*)d_in[9];
    const float* a_post = (const float*)d_in[10];
    const float* a_res  = (const float*)d_in[11];
    short* Wb  = (short*)d_ws;              // 192*2048 bf16 = 786 KB
    float* out = (float*)d_out;

    prep_w_kernel<<<dim3(NOUT), dim3(256), 0, stream>>>(
        norm_w, p_pre, p_post, p_res, act, Wb);
    mhc_mfma_kernel<<<dim3(512), dim3(256), 0, stream>>>(
        x, Wb, act, b_pre, b_post, b_res, a_pre, a_post, a_res, out);
}